// Round 6
// baseline (502.841 us; speedup 1.0000x reference)
//
#include <hip/hip_runtime.h>
#include <hip/hip_bf16.h>
#include <math.h>

// Problem constants
#define B_  8
#define L_  128
#define V_  32000
#define D_  64
#define R1_ 128
#define R2_ 320
#define UP_ 640
#define SPLITS_ 50   // k-splits for stage A (640 k each)

typedef short bf16x8 __attribute__((ext_vector_type(8)));
typedef float f32x4 __attribute__((ext_vector_type(4)));

#define GLDS16(gp, lp)                                                         \
    __builtin_amdgcn_global_load_lds(                                          \
        (const __attribute__((address_space(1))) void*)(gp),                   \
        (__attribute__((address_space(3))) void*)(lp), 16, 0, 0)

static __device__ inline unsigned short f2bf(float x) {
    __hip_bfloat16 h = __float2bfloat16(x);
    return *reinterpret_cast<unsigned short*>(&h);
}

// hi/lo bf16 split: v ~= hi + lo with rel err ~2^-17
static __device__ inline void split1(float v, unsigned short& h, unsigned short& l) {
    unsigned short hb = f2bf(v);
    float hf = __uint_as_float(((unsigned int)hb) << 16);
    h = hb;
    l = f2bf(v - hf);
}

// ---------------------------------------------------------------------------
// prep_weights: one launch, three jobs (block = 320 threads).
//   bx [0,800):      W_emb[64][32000] fp32 -> k-blocked bf16 hi/lo
//                    (unit u = kb*64+row holds that row's k-range [kb*8,kb*8+8))
//   bx [800,4896):   Wup2 fp32 -> bf16 (grid-stride over float4s)
//   bx [4896,5280):  positional-encoding stage kernels (3 stages x 128 l)
__global__ __launch_bounds__(320) void prep_weights(
    const float* __restrict__ Wemb, unsigned short* __restrict__ Whb,
    unsigned short* __restrict__ Wlb, const float* __restrict__ Wup2,
    unsigned short* __restrict__ Wup2b,
    const float* __restrict__ W1, const float* __restrict__ b1, float* __restrict__ o1,
    const float* __restrict__ W2, const float* __restrict__ b2, float* __restrict__ o2,
    const float* __restrict__ W3, const float* __restrict__ b3, float* __restrict__ o3) {
    __shared__ float P[640];
    int bx = blockIdx.x, t = threadIdx.x;
    if (bx < 800) {
        int u = bx * 320 + t;   // 0 .. 255999
        int kb = u >> 6, row = u & 63;
        const float* s = Wemb + (size_t)row * 32000 + kb * 8;
        unsigned short h8[8], l8[8];
#pragma unroll
        for (int j = 0; j < 8; ++j) split1(s[j], h8[j], l8[j]);
        *(ushort4*)&Whb[(size_t)u * 8]     = *(ushort4*)&h8[0];
        *(ushort4*)&Whb[(size_t)u * 8 + 4] = *(ushort4*)&h8[4];
        *(ushort4*)&Wlb[(size_t)u * 8]     = *(ushort4*)&l8[0];
        *(ushort4*)&Wlb[(size_t)u * 8 + 4] = *(ushort4*)&l8[4];
    } else if (bx < 4896) {
        const int n4 = (V_ * UP_) / 4;
        int stride = 4096 * 320;
        for (int i = (bx - 800) * 320 + t; i < n4; i += stride) {
            float4 v = ((const float4*)Wup2)[i];
            ushort4 o;
            o.x = f2bf(v.x); o.y = f2bf(v.y); o.z = f2bf(v.z); o.w = f2bf(v.w);
            ((ushort4*)Wup2b)[i] = o;
        }
    } else {
        int idx = bx - 4896;
        int stage = idx >> 7;        // 0..2
        int l = idx & 127;
        const float* W = (stage == 0) ? W1 : (stage == 1) ? W2 : W3;
        const float* bias = (stage == 0) ? b1 : (stage == 1) ? b2 : b3;
        float* out = (stage == 0) ? o1 : (stage == 1) ? o2 : o3;
        int outF = (stage == 0) ? 64 : (stage == 1) ? 128 : 320;
        int dEnc = 2 * outF;
        for (int m = t; m < dEnc; m += 320) {
            int i = m >> 1;
            float ang = (float)l * powf(10000.0f, -2.0f * (float)i / (float)dEnc);
            P[m] = (m & 1) ? cosf(ang) : sinf(ang);
        }
        __syncthreads();
        if (t < outF) {
            float acc = bias[t];
            const float4* w = (const float4*)(W + (size_t)t * dEnc);
            for (int m4 = 0; m4 < dEnc / 4; ++m4) {
                float4 wv = w[m4];
                float4 pv = *(const float4*)&P[m4 * 4];
                acc = fmaf(pv.x, wv.x, acc);
                acc = fmaf(pv.y, wv.y, acc);
                acc = fmaf(pv.z, wv.z, acc);
                acc = fmaf(pv.w, wv.w, acc);
            }
            out[l * outF + t] = fmaxf(acc, 0.f);
        }
    }
}

// ---------------------------------------------------------------------------
// Stage A via MFMA, 3-product bf16 split, software-pipelined (dbuf GLDS16 W,
// VGPR-prefetched x split in-register). partA[split][row][d].
// grid: (16 rowblocks of 64, SPLITS_), block 256.
__global__ __launch_bounds__(256) void embA_mfma(const float* __restrict__ x,
                                                 const unsigned short* __restrict__ Whb,
                                                 const unsigned short* __restrict__ Wlb,
                                                 float* __restrict__ partA) {
    __shared__ short lds[16384];   // 2 x 16 KB
    int t = threadIdx.x;
    int lane = t & 63, w = t >> 6;
    int ln = lane & 15, lg = lane >> 4;
    int rb = blockIdx.x, ks = blockIdx.y;
    int row0 = rb * 64;
    const float* xrow = x + (size_t)(row0 + w * 16 + ln) * 32000;

    f32x4 acc[4];
#pragma unroll
    for (int nt = 0; nt < 4; ++nt) acc[nt] = (f32x4){0.f, 0.f, 0.f, 0.f};

    float4 xc[4], xn[4];
    {
        int kb0 = (ks * 640) >> 3;
#pragma unroll
        for (int s = 0; s < 4; ++s) {
            int ubase = s * 256 + w * 64;
            const unsigned short* arr = (s < 2) ? Whb : Wlb;
            int uu = (s < 2) ? ubase : (ubase - 512);
            const char* gp = (const char*)arr + ((size_t)kb0 * 64 + uu + lane) * 16;
            char* lp = (char*)lds + ((s < 2) ? 0 : 8192) + uu * 16;
            GLDS16(gp, lp);
        }
        const float* bp = xrow + ks * 640 + lg * 8;
        xc[0] = ((const float4*)bp)[0];
        xc[1] = ((const float4*)bp)[1];
        xc[2] = ((const float4*)(bp + 32))[0];
        xc[3] = ((const float4*)(bp + 32))[1];
    }

#pragma unroll 2
    for (int ch = 0; ch < 10; ++ch) {
        __syncthreads();   // drains chunk-ch GLDS16 + x loads
        if (ch < 9) {      // kick chunk ch+1 into the other buffer
            int kb0 = (ks * 640 + (ch + 1) * 64) >> 3;
            int p = (ch + 1) & 1;
#pragma unroll
            for (int s = 0; s < 4; ++s) {
                int ubase = s * 256 + w * 64;
                const unsigned short* arr = (s < 2) ? Whb : Wlb;
                int uu = (s < 2) ? ubase : (ubase - 512);
                const char* gp = (const char*)arr + ((size_t)kb0 * 64 + uu + lane) * 16;
                char* lp = (char*)lds + p * 16384 + ((s < 2) ? 0 : 8192) + uu * 16;
                GLDS16(gp, lp);
            }
            const float* bp = xrow + ks * 640 + (ch + 1) * 64 + lg * 8;
            xn[0] = ((const float4*)bp)[0];
            xn[1] = ((const float4*)bp)[1];
            xn[2] = ((const float4*)(bp + 32))[0];
            xn[3] = ((const float4*)(bp + 32))[1];
        }
        bf16x8 ah[2], al[2];
#pragma unroll
        for (int kstep = 0; kstep < 2; ++kstep) {
            float f[8] = {xc[2 * kstep].x, xc[2 * kstep].y, xc[2 * kstep].z, xc[2 * kstep].w,
                          xc[2 * kstep + 1].x, xc[2 * kstep + 1].y, xc[2 * kstep + 1].z,
                          xc[2 * kstep + 1].w};
            unsigned short h8[8], l8[8];
#pragma unroll
            for (int j = 0; j < 8; ++j) split1(f[j], h8[j], l8[j]);
            ah[kstep] = *(bf16x8*)h8;
            al[kstep] = *(bf16x8*)l8;
        }
        const char* buf = (const char*)lds + (ch & 1) * 16384;
#pragma unroll
        for (int kstep = 0; kstep < 2; ++kstep) {
            int g = kstep * 4 + lg;
#pragma unroll
            for (int nt = 0; nt < 4; ++nt) {
                int nrow = nt * 16 + ln;
                bf16x8 bh = *(const bf16x8*)(buf + (g * 64 + nrow) * 16);
                bf16x8 bl = *(const bf16x8*)(buf + 8192 + (g * 64 + nrow) * 16);
                acc[nt] = __builtin_amdgcn_mfma_f32_16x16x32_bf16(ah[kstep], bh, acc[nt], 0, 0, 0);
                acc[nt] = __builtin_amdgcn_mfma_f32_16x16x32_bf16(ah[kstep], bl, acc[nt], 0, 0, 0);
                acc[nt] = __builtin_amdgcn_mfma_f32_16x16x32_bf16(al[kstep], bh, acc[nt], 0, 0, 0);
            }
        }
#pragma unroll
        for (int i = 0; i < 4; ++i) xc[i] = xn[i];
    }
#pragma unroll
    for (int nt = 0; nt < 4; ++nt)
#pragma unroll
        for (int r = 0; r < 4; ++r)
            partA[((size_t)ks * 1024 + row0 + w * 16 + lg * 4 + r) * 64 + nt * 16 + ln] =
                acc[nt][r];
}

// ---------------------------------------------------------------------------
// reduceA v2: 4 rows/block (one per wave). h1[row,d] = relu(sum_s partA +
// b_emb[d]) + pe1[l,d]; s1[row] = sum_d h1. grid 256, block 256.
__global__ __launch_bounds__(256) void reduceA_kernel(const float* __restrict__ partA,
                                                      const float* __restrict__ bemb,
                                                      const float* __restrict__ pe1,
                                                      float* __restrict__ h1,
                                                      float* __restrict__ s1) {
    int t = threadIdx.x;
    int d = t & 63;
    int row = blockIdx.x * 4 + (t >> 6);
    int l = row & 127;
    float v = bemb[d];
#pragma unroll 10
    for (int s = 0; s < SPLITS_; ++s) v += partA[((size_t)s * 1024 + row) * 64 + d];
    v = fmaxf(v, 0.f) + pe1[l * 64 + d];
    h1[row * 64 + d] = v;
    float sum = v;
    for (int off = 32; off > 0; off >>= 1) sum += __shfl_down(sum, off);
    if (d == 0) s1[row] = sum;
}

// ---------------------------------------------------------------------------
// wr1: Wr1[b,r,j] = sum_k s1[b,k] * W_red[r, k*64+j]
__global__ __launch_bounds__(64) void wr1_kernel(const float* __restrict__ Wred,
                                                 const float* __restrict__ s1,
                                                 float* __restrict__ Wr1) {
    __shared__ float ss[8 * 128];
    int r = blockIdx.x;
    int j = threadIdx.x;
    for (int idx = j; idx < 1024; idx += 64) ss[idx] = s1[idx];
    __syncthreads();
    float acc[8];
#pragma unroll
    for (int b = 0; b < 8; ++b) acc[b] = 0.f;
    const float* w = Wred + (size_t)r * 8192 + j;
    for (int k = 0; k < 128; ++k) {
        float wv = w[k * 64];
#pragma unroll
        for (int b = 0; b < 8; ++b) acc[b] = fmaf(ss[b * 128 + k], wv, acc[b]);
    }
#pragma unroll
    for (int b = 0; b < 8; ++b) Wr1[((size_t)b * 128 + r) * 64 + j] = acc[b];
}

// ---------------------------------------------------------------------------
// h2: h2[b,i,r] = relu(sum_j h1[b,i,j]*Wr1[b,r,j] + b_red[r]) + pe2[i,r]; s2=sum_r
__global__ __launch_bounds__(128) void h2_kernel(const float* __restrict__ h1,
                                                 const float* __restrict__ Wr1,
                                                 const float* __restrict__ bred,
                                                 const float* __restrict__ pe2,
                                                 float* __restrict__ h2,
                                                 float* __restrict__ s2) {
    __shared__ float hrow[64];
    __shared__ float red[2];
    int row = blockIdx.x;
    int b = row >> 7, i = row & 127;
    int r = threadIdx.x;
    if (r < 64) hrow[r] = h1[row * 64 + r];
    __syncthreads();
    float acc = bred[r];
    const float4* w = (const float4*)(Wr1 + ((size_t)b * 128 + r) * 64);
#pragma unroll
    for (int j4 = 0; j4 < 16; ++j4) {
        float4 wv = w[j4];
        float4 hv = *(const float4*)&hrow[j4 * 4];
        acc = fmaf(hv.x, wv.x, acc);
        acc = fmaf(hv.y, wv.y, acc);
        acc = fmaf(hv.z, wv.z, acc);
        acc = fmaf(hv.w, wv.w, acc);
    }
    float val = fmaxf(acc, 0.f) + pe2[i * 128 + r];
    h2[row * 128 + r] = val;
    float sum = val;
    for (int off = 32; off > 0; off >>= 1) sum += __shfl_down(sum, off);
    if ((r & 63) == 0) red[r >> 6] = sum;
    __syncthreads();
    if (r == 0) s2[row] = red[0] + red[1];
}

// ---------------------------------------------------------------------------
// wr2: Wr2[b,r2,j] = sum_k s2[b,k] * W_red2[r2, k*128+j]
__global__ __launch_bounds__(128) void wr2_kernel(const float* __restrict__ Wred2,
                                                  const float* __restrict__ s2,
                                                  float* __restrict__ Wr2) {
    __shared__ float ss[8 * 128];
    int r = blockIdx.x;
    int j = threadIdx.x;
    for (int idx = j; idx < 1024; idx += 128) ss[idx] = s2[idx];
    __syncthreads();
    float acc[8];
#pragma unroll
    for (int b = 0; b < 8; ++b) acc[b] = 0.f;
    const float* w = Wred2 + (size_t)r * 16384 + j;
    for (int k = 0; k < 128; ++k) {
        float wv = w[k * 128];
#pragma unroll
        for (int b = 0; b < 8; ++b) acc[b] = fmaf(ss[b * 128 + k], wv, acc[b]);
    }
#pragma unroll
    for (int b = 0; b < 8; ++b) Wr2[((size_t)b * 320 + r) * 128 + j] = acc[b];
}

// ---------------------------------------------------------------------------
// h3: h3[b,i,r2] = relu(sum_j h2[b,i,j]*Wr2[b,r2,j] + b_red2[r2]) + pe3[i,r2]
__global__ __launch_bounds__(320) void h3_kernel(const float* __restrict__ h2,
                                                 const float* __restrict__ Wr2,
                                                 const float* __restrict__ bred2,
                                                 const float* __restrict__ pe3,
                                                 float* __restrict__ h3) {
    __shared__ float hrow[128];
    int row = blockIdx.x;
    int b = row >> 7, i = row & 127;
    int r = threadIdx.x;
    if (r < 128) hrow[r] = h2[row * 128 + r];
    __syncthreads();
    float acc = bred2[r];
    const float4* w = (const float4*)(Wr2 + ((size_t)b * 320 + r) * 128);
#pragma unroll
    for (int j4 = 0; j4 < 32; ++j4) {
        float4 wv = w[j4];
        float4 hv = *(const float4*)&hrow[j4 * 4];
        acc = fmaf(hv.x, wv.x, acc);
        acc = fmaf(hv.y, wv.y, acc);
        acc = fmaf(hv.z, wv.z, acc);
        acc = fmaf(hv.w, wv.w, acc);
    }
    h3[(size_t)row * 320 + r] = fmaxf(acc, 0.f) + pe3[i * 320 + r];
}

// ---------------------------------------------------------------------------
// h4 v4: 8 rows/block, u-halves on grid y. grid (128, 2), block 320.
// h4b[row,u] = bf16(relu(sum_k h3[row,k]*Wup1[u,k] + b_up1[u]))
// Wup1 per-thread float4 row reads (L1-line fully consumed); h3 staged in LDS
// as hsT[j][q] so inner reads are same-address broadcasts (conflict-free).
__global__ __launch_bounds__(320) void h4_kernel(const float* __restrict__ h3,
                                                 const float* __restrict__ Wup1,
                                                 const float* __restrict__ bup1,
                                                 unsigned short* __restrict__ h4b) {
    __shared__ float hsT[320 * 8];
    int t = threadIdx.x;
    int row0 = blockIdx.x * 8;
    int u = blockIdx.y * 320 + t;
#pragma unroll
    for (int p = 0; p < 8; ++p)
        hsT[t * 8 + p] = h3[(size_t)(row0 + p) * 320 + t];
    __syncthreads();
    float acc[8];
#pragma unroll
    for (int q = 0; q < 8; ++q) acc[q] = 0.f;
    const float4* w = (const float4*)(Wup1 + (size_t)u * 320);
#pragma unroll 2
    for (int j4 = 0; j4 < 80; ++j4) {
        float4 wv = w[j4];
#pragma unroll
        for (int e = 0; e < 4; ++e) {
            float wc = (e == 0) ? wv.x : (e == 1) ? wv.y : (e == 2) ? wv.z : wv.w;
            const float4* hp = (const float4*)&hsT[(j4 * 4 + e) * 8];
            float4 h0 = hp[0], h1v = hp[1];
            acc[0] = fmaf(h0.x, wc, acc[0]);
            acc[1] = fmaf(h0.y, wc, acc[1]);
            acc[2] = fmaf(h0.z, wc, acc[2]);
            acc[3] = fmaf(h0.w, wc, acc[3]);
            acc[4] = fmaf(h1v.x, wc, acc[4]);
            acc[5] = fmaf(h1v.y, wc, acc[5]);
            acc[6] = fmaf(h1v.z, wc, acc[6]);
            acc[7] = fmaf(h1v.w, wc, acc[7]);
        }
    }
    float bias = bup1[u];
#pragma unroll
    for (int q = 0; q < 8; ++q)
        h4b[(size_t)(row0 + q) * 640 + u] = f2bf(fmaxf(acc[q] + bias, 0.f));
}

// ---------------------------------------------------------------------------
// final MFMA kernel, 2-batch tile: 128v x (2b x 128l), 512 thr (8 waves), BK=64.
// XCD-swizzled 1D grid (1024, 24 idle): the 4 blocks sharing an A-tile (same
// v-tile, different batch-pair) get linear ids differing by 8 -> same XCD L2.
__global__ __launch_bounds__(512) void final_mfma_kernel(
    const unsigned short* __restrict__ h4b,
    const unsigned short* __restrict__ Wup2b,
    const float* __restrict__ bup2,
    const float* __restrict__ Wfin,
    const float* __restrict__ bfin,
    float* __restrict__ out) {
    __shared__ short tile[24576];          // 48 KB: A | B0 | B1
    __shared__ float redbuf[2][2][128];    // [b_local][l_half][v]

    // swizzle decode: g = G*32 + y*8 + v8 ; v_tile = G*8 + v8 ; batch-pair = y
    int g = blockIdx.x;
    int G = g >> 5, rbits = g & 31;
    int y = rbits >> 3, v8 = rbits & 7;
    int vt = G * 8 + v8;
    if (vt >= 250) return;
    int v0 = vt * 128;
    int b0 = y * 2;

    int t = threadIdx.x;
    int lane = t & 63;
    int w = t >> 6;                 // 0..7
    int wv = w >> 2;                // v-half 0..1
    int wq = w & 3;                 // b_local = wq>>1, l_half = wq&1
    int bl_ = wq >> 1, lh = wq & 1;
    int ln = lane & 15, lg = lane >> 4;

    f32x4 acc[4][4];
#pragma unroll
    for (int mt = 0; mt < 4; ++mt)
#pragma unroll
        for (int nt = 0; nt < 4; ++nt) acc[mt][nt] = (f32x4){0.f, 0.f, 0.f, 0.f};

    for (int ch = 0; ch < 10; ++ch) {
        int k0 = ch * 64;
        __syncthreads();
#pragma unroll
        for (int s = 0; s < 6; ++s) {
            int F = (w * 6 + s) * 1024 + lane * 16;    // byte offset in 48 KB
            int region = F >> 14;                       // 0=A, 1=B0, 2=B1
            int rr = (F >> 7) & 127;                    // row within region
            int gg = ((F >> 4) & 7) ^ (rr & 7);         // logical k-block
            size_t rowG = (region == 0) ? (size_t)(v0 + rr)
                                        : (size_t)((b0 + region - 1) * 128 + rr);
            const unsigned short* base = (region == 0) ? Wup2b : h4b;
            const char* gp = (const char*)base + (rowG * 640 + (size_t)(k0 + gg * 8)) * 2;
            char* lp = (char*)tile + (w * 6 + s) * 1024;   // wave-uniform
            GLDS16(gp, lp);
        }
        __syncthreads();
#pragma unroll
        for (int ks = 0; ks < 2; ++ks) {
            bf16x8 aF[4], bF[4];
#pragma unroll
            for (int mt = 0; mt < 4; ++mt) {
                int rA = wv * 64 + mt * 16 + ln;
                int gg = ks * 4 + lg;
                int off = rA * 128 + ((gg ^ (rA & 7)) * 16);
                aF[mt] = *(const bf16x8*)((const char*)tile + off);
            }
#pragma unroll
            for (int nt = 0; nt < 4; ++nt) {
                int rB = lh * 64 + nt * 16 + ln;
                int gg = ks * 4 + lg;
                int off = (1 + bl_) * 16384 + rB * 128 + ((gg ^ (rB & 7)) * 16);
                bF[nt] = *(const bf16x8*)((const char*)tile + off);
            }
#pragma unroll
            for (int mt = 0; mt < 4; ++mt)
#pragma unroll
                for (int nt = 0; nt < 4; ++nt)
                    acc[mt][nt] = __builtin_amdgcn_mfma_f32_16x16x32_bf16(
                        aF[mt], bF[nt], acc[mt][nt], 0, 0, 0);
        }
    }

    // Epilogue: C/D layout col(l)=lane&15, row(v)=(lane>>4)*4+reg
    float bfin0 = bfin[0];
#pragma unroll
    for (int mt = 0; mt < 4; ++mt) {
        float bu[4];
#pragma unroll
        for (int r = 0; r < 4; ++r)
            bu[r] = bup2[v0 + wv * 64 + mt * 16 + lg * 4 + r];
        float part[4] = {0.f, 0.f, 0.f, 0.f};
#pragma unroll
        for (int nt = 0; nt < 4; ++nt) {
            float wf = Wfin[lh * 64 + nt * 16 + ln];
#pragma unroll
            for (int r = 0; r < 4; ++r)
                part[r] += wf * fmaxf(acc[mt][nt][r] + bu[r], 0.f);
        }
#pragma unroll
        for (int off = 8; off >= 1; off >>= 1)
#pragma unroll
            for (int r = 0; r < 4; ++r) part[r] += __shfl_xor(part[r], off, 64);
        if (ln == 0) {
#pragma unroll
            for (int r = 0; r < 4; ++r)
                redbuf[bl_][lh][wv * 64 + mt * 16 + lg * 4 + r] = part[r];
        }
    }
    __syncthreads();
    if (t < 256) {
        int bb = t >> 7, v = t & 127;
        float vsum = redbuf[bb][0][v] + redbuf[bb][1][v] + bfin0;
        out[(size_t)(b0 + bb) * 32000 + v0 + v] = fmaxf(vsum, 0.f);
    }
}

// ---------------------------------------------------------------------------
extern "C" void kernel_launch(void* const* d_in, const int* in_sizes, int n_in,
                              void* d_out, int out_size, void* d_ws, size_t ws_size,
                              hipStream_t stream) {
    const float* x      = (const float*)d_in[0];
    const float* W_emb  = (const float*)d_in[1];
    const float* b_emb  = (const float*)d_in[2];
    const float* W_pos1 = (const float*)d_in[3];
    const float* b_pos1 = (const float*)d_in[4];
    const float* W_red  = (const float*)d_in[5];
    const float* b_red  = (const float*)d_in[6];
    const float* W_pos2 = (const float*)d_in[7];
    const float* b_pos2 = (const float*)d_in[8];
    const float* W_red2 = (const float*)d_in[9];
    const float* b_red2 = (const float*)d_in[10];
    const float* W_pos3 = (const float*)d_in[11];
    const float* b_pos3 = (const float*)d_in[12];
    const float* W_up1  = (const float*)d_in[13];
    const float* b_up1  = (const float*)d_in[14];
    const float* W_up2  = (const float*)d_in[15];
    const float* b_up2  = (const float*)d_in[16];
    const float* W_fin  = (const float*)d_in[17];
    const float* b_fin  = (const float*)d_in[18];
    float* out = (float*)d_out;

    float* ws  = (float*)d_ws;
    float* pe1 = ws;                 // 8192
    float* pe2 = pe1 + 8192;         // 16384
    float* pe3 = pe2 + 16384;        // 40960
    float* h1  = pe3 + 40960;        // 65536
    float* s1  = h1 + 65536;         // 1024
    float* Wr1 = s1 + 1024;          // 65536
    float* h2  = Wr1 + 65536;        // 131072
    float* s2  = h2 + 131072;        // 1024
    float* Wr2 = s2 + 1024;          // 327680
    float* h3  = Wr2 + 327680;       // 327680
    unsigned short* h4b   = (unsigned short*)(h3 + 327680);          // 655360 shorts
    unsigned short* Wup2b = (unsigned short*)((float*)h4b + 327680); // 20,480,000 shorts
    float* after = (float*)Wup2b + 10240000;
    unsigned short* Whb = (unsigned short*)after;             // 2,048,000 shorts
    unsigned short* Wlb = Whb + 2048000;                      // 2,048,000 shorts
    float* partA = (float*)(Wlb + 2048000);                   // 3,276,800 floats
    // total ws use ~73 MB

    prep_weights<<<dim3(5280), 320, 0, stream>>>(W_emb, Whb, Wlb, W_up2, Wup2b,
                                                 W_pos1, b_pos1, pe1,
                                                 W_pos2, b_pos2, pe2,
                                                 W_pos3, b_pos3, pe3);
    embA_mfma<<<dim3(16, SPLITS_), 256, 0, stream>>>(x, Whb, Wlb, partA);
    reduceA_kernel<<<dim3(256), 256, 0, stream>>>(partA, b_emb, pe1, h1, s1);
    wr1_kernel<<<dim3(128), 64, 0, stream>>>(W_red, s1, Wr1);
    h2_kernel<<<dim3(1024), 128, 0, stream>>>(h1, Wr1, b_red, pe2, h2, s2);
    wr2_kernel<<<dim3(320), 128, 0, stream>>>(W_red2, s2, Wr2);
    h3_kernel<<<dim3(1024), 320, 0, stream>>>(h2, Wr2, b_red2, pe3, h3);
    h4_kernel<<<dim3(128, 2), 320, 0, stream>>>(h3, W_up1, b_up1, h4b);
    final_mfma_kernel<<<dim3(1024), 512, 0, stream>>>(h4b, Wup2b, b_up2, W_fin,
                                                      b_fin, out);
}